// Round 1
// baseline (204.477 us; speedup 1.0000x reference)
//
#include <hip/hip_runtime.h>

typedef __attribute__((ext_vector_type(4))) float fx4;
typedef __attribute__((ext_vector_type(8))) short s16x8;

#define QK_SCALE 0.35355339059327373f  // 1/sqrt(sqrt(64))

__device__ __forceinline__ short f2bf(float f) {
  union { float f; unsigned int u; } v; v.f = f;
  unsigned int r = v.u + 0x7fffu + ((v.u >> 16) & 1u);  // RNE
  return (short)(r >> 16);
}

// XOR swizzle for [rows][64 bf16] LDS tiles (128 B row stride):
// physical byte = (row*128 + cb) ^ ((row&7)<<4). Involution; keeps 16B chunks intact.
__device__ __forceinline__ int swz(int row, int cb) {
  return (row * 128 + cb) ^ ((row & 7) << 4);
}

#define GLL(g, lds) __builtin_amdgcn_global_load_lds( \
    (__attribute__((address_space(1))) void*)(void*)(g), \
    (__attribute__((address_space(3))) void*)(void*)(lds), 16, 0, 0)

// ---------------- conversion kernels ----------------
__global__ __launch_bounds__(256) void cvt_bf16(const float* __restrict__ in,
                                                short* __restrict__ out, int n4) {
  int i = blockIdx.x * 256 + threadIdx.x;
  if (i < n4) {
    float4 v = reinterpret_cast<const float4*>(in)[i];
    short4 o;
    o.x = f2bf(v.x); o.y = f2bf(v.y); o.z = f2bf(v.z); o.w = f2bf(v.w);
    reinterpret_cast<short4*>(out)[i] = o;
  }
}

// W [K][N] fp32 -> WT [N][K] bf16, LDS-tiled (coalesced both sides)
__global__ __launch_bounds__(256) void transpose_cvt(const float* __restrict__ W,
                                                     short* __restrict__ WT,
                                                     int K, int N) {
  __shared__ float tile[32][33];
  int tx = threadIdx.x, ty = threadIdx.y;
  int n0 = blockIdx.x * 32, k0 = blockIdx.y * 32;
#pragma unroll
  for (int i = 0; i < 32; i += 8)
    tile[ty + i][tx] = W[(size_t)(k0 + ty + i) * N + n0 + tx];
  __syncthreads();
#pragma unroll
  for (int i = 0; i < 32; i += 8)
    WT[(size_t)(n0 + ty + i) * K + k0 + tx] = f2bf(tile[tx][ty + i]);
}

// ---------------- GEMM: C[M][N] = A[M][K] @ Bt[N][K]^T (+bias) ----------------
// MODE 0: qkv epilogue -> scatter Q,K (scaled) [bh][t][64], V transposed [bh][64][t], bf16
// MODE 1: plain fp32 out + bias
template <int MODE>
__global__ __launch_bounds__(256) void gemm_bf16(
    const short* __restrict__ A, const short* __restrict__ Bt,
    const float* __restrict__ bias, float* __restrict__ Cout,
    short* __restrict__ Qo, short* __restrict__ Ko, short* __restrict__ Vo,
    int M, int N, int K) {
  __shared__ __align__(16) char sA[128 * 64 * 2];
  __shared__ __align__(16) char sB[128 * 64 * 2];
  const int tid = threadIdx.x;
  const int w = tid >> 6, l = tid & 63;
  const int lr = l & 15, lg = l >> 4;
  const int m0 = blockIdx.y * 128, n0 = blockIdx.x * 128;
  const int wr = (w >> 1) * 64, wc = (w & 1) * 64;

  fx4 acc[4][4] = {};

  for (int kt = 0; kt < K; kt += 64) {
#pragma unroll
    for (int i = 0; i < 4; ++i) {
      int c = i * 256 + tid;
      int r = c >> 3, p = c & 7;
      int lch = p ^ (r & 7);  // pre-swizzled global source, linear LDS dest
      GLL(A + (size_t)(m0 + r) * K + kt + lch * 8, sA + c * 16);
      GLL(Bt + (size_t)(n0 + r) * K + kt + lch * 8, sB + c * 16);
    }
    __syncthreads();
#pragma unroll
    for (int kk = 0; kk < 2; ++kk) {
      s16x8 av[4], bv[4];
#pragma unroll
      for (int m = 0; m < 4; ++m)
        av[m] = *reinterpret_cast<const s16x8*>(sA + swz(wr + m * 16 + lr, kk * 64 + lg * 16));
#pragma unroll
      for (int n = 0; n < 4; ++n)
        bv[n] = *reinterpret_cast<const s16x8*>(sB + swz(wc + n * 16 + lr, kk * 64 + lg * 16));
#pragma unroll
      for (int m = 0; m < 4; ++m)
#pragma unroll
        for (int n = 0; n < 4; ++n)
          acc[m][n] = __builtin_amdgcn_mfma_f32_16x16x32_bf16(av[m], bv[n], acc[m][n], 0, 0, 0);
    }
    __syncthreads();
  }

#pragma unroll
  for (int m = 0; m < 4; ++m) {
#pragma unroll
    for (int n = 0; n < 4; ++n) {
#pragma unroll
      for (int q = 0; q < 4; ++q) {
        int row = m0 + wr + m * 16 + lg * 4 + q;   // C/D: row=(lane>>4)*4+reg
        int col = n0 + wc + n * 16 + lr;           //      col=lane&15
        float v = acc[m][n][q] + bias[col];
        if (MODE == 1) {
          Cout[(size_t)row * N + col] = v;
        } else {
          int h = col / 192;          // qkv interleave: [h][q(64)|k(64)|v(64)]
          int rr = col - h * 192;
          int b = row >> 11, t = row & 2047;
          size_t bh = (size_t)b * 16 + h;
          if (rr < 64)
            Qo[(bh * 2048 + t) * 64 + rr] = f2bf(v * QK_SCALE);
          else if (rr < 128)
            Ko[(bh * 2048 + t) * 64 + (rr - 64)] = f2bf(v * QK_SCALE);
          else
            Vo[(bh * 64 + (rr - 128)) * 2048 + t] = f2bf(v);
        }
      }
    }
  }
}

// ---------------- flash attention ----------------
// grid (32 q-tiles, 32 bh); 4 waves/block, 16 q-rows per wave; s-tiles of 64.
__global__ __launch_bounds__(256) void attn_fwd(
    const short* __restrict__ Q, const short* __restrict__ Kc,
    const short* __restrict__ VT, short* __restrict__ Y) {
  __shared__ __align__(16) char sK[64 * 64 * 2];
  __shared__ __align__(16) char sV[64 * 64 * 2];
  __shared__ __align__(16) char sP[4][16 * 64 * 2];
  const int tid = threadIdx.x;
  const int w = tid >> 6, l = tid & 63;
  const int lr = l & 15, lg = l >> 4;
  const int bh = blockIdx.y;
  const int qt = blockIdx.x;

  // Q fragments held in registers: A-frag lane holds Q[q0+lane%16][(lane/16)*8+j (+32*kk)]
  s16x8 aq[2];
#pragma unroll
  for (int kk = 0; kk < 2; ++kk)
    aq[kk] = *reinterpret_cast<const s16x8*>(
        Q + ((size_t)bh * 2048 + qt * 64 + w * 16 + lr) * 64 + kk * 32 + lg * 8);

  float mrow[4], lrow[4];
#pragma unroll
  for (int q = 0; q < 4; ++q) { mrow[q] = -1e30f; lrow[q] = 0.f; }
  fx4 o[4] = {};

  for (int sb = 0; sb < 32; ++sb) {
    const int s0 = sb * 64;
#pragma unroll
    for (int i = 0; i < 2; ++i) {
      int c = i * 256 + tid;
      int r = c >> 3, p = c & 7;
      int lch = p ^ (r & 7);
      GLL(Kc + ((size_t)bh * 2048 + s0 + r) * 64 + lch * 8, sK + c * 16);
      GLL(VT + ((size_t)bh * 64 + r) * 2048 + s0 + lch * 8, sV + c * 16);
    }
    __syncthreads();

    // S = Q K^T  (Q,K pre-scaled by 1/sqrt(8))
    fx4 sa[4] = {};
#pragma unroll
    for (int kk = 0; kk < 2; ++kk)
#pragma unroll
      for (int n = 0; n < 4; ++n) {
        s16x8 bk = *reinterpret_cast<const s16x8*>(sK + swz(n * 16 + lr, kk * 64 + lg * 16));
        sa[n] = __builtin_amdgcn_mfma_f32_16x16x32_bf16(aq[kk], bk, sa[n], 0, 0, 0);
      }

    // online softmax; row r=(lg*4+q) lives in the 16 lanes sharing lg
    float pm[4];
#pragma unroll
    for (int q = 0; q < 4; ++q)
      pm[q] = fmaxf(fmaxf(sa[0][q], sa[1][q]), fmaxf(sa[2][q], sa[3][q]));
#pragma unroll
    for (int msk = 1; msk < 16; msk <<= 1)
#pragma unroll
      for (int q = 0; q < 4; ++q)
        pm[q] = fmaxf(pm[q], __shfl_xor(pm[q], msk));

    float al[4], rs[4];
#pragma unroll
    for (int q = 0; q < 4; ++q) {
      float mn = fmaxf(mrow[q], pm[q]);
      al[q] = __expf(mrow[q] - mn);
      mrow[q] = mn;
      rs[q] = 0.f;
    }
#pragma unroll
    for (int n = 0; n < 4; ++n)
#pragma unroll
      for (int q = 0; q < 4; ++q) {
        float p = __expf(sa[n][q] - mrow[q]);
        sa[n][q] = p;
        rs[q] += p;
      }
#pragma unroll
    for (int msk = 1; msk < 16; msk <<= 1)
#pragma unroll
      for (int q = 0; q < 4; ++q)
        rs[q] += __shfl_xor(rs[q], msk);
#pragma unroll
    for (int q = 0; q < 4; ++q)
      lrow[q] = lrow[q] * al[q] + rs[q];
#pragma unroll
    for (int n = 0; n < 4; ++n)
#pragma unroll
      for (int q = 0; q < 4; ++q)
        o[n][q] *= al[q];

    // P (C-layout) -> per-wave LDS (swizzled) -> A-frags
    char* pw = sP[w];
#pragma unroll
    for (int n = 0; n < 4; ++n)
#pragma unroll
      for (int q = 0; q < 4; ++q) {
        int row = lg * 4 + q, colb = (n * 16 + lr) * 2;
        *reinterpret_cast<short*>(pw + ((row * 128 + colb) ^ ((row & 7) << 4))) =
            f2bf(sa[n][q]);
      }

#pragma unroll
    for (int kk = 0; kk < 2; ++kk) {
      s16x8 ap = *reinterpret_cast<const s16x8*>(pw + swz(lr, kk * 64 + lg * 16));
#pragma unroll
      for (int n = 0; n < 4; ++n) {
        s16x8 bv = *reinterpret_cast<const s16x8*>(sV + swz(n * 16 + lr, kk * 64 + lg * 16));
        o[n] = __builtin_amdgcn_mfma_f32_16x16x32_bf16(ap, bv, o[n], 0, 0, 0);
      }
    }
    __syncthreads();
  }

  const int b = bh >> 4, h = bh & 15;
#pragma unroll
  for (int q = 0; q < 4; ++q) {
    float inv = 1.0f / lrow[q];
#pragma unroll
    for (int n = 0; n < 4; ++n) {
      int t = qt * 64 + w * 16 + lg * 4 + q;
      Y[((size_t)b * 2048 + t) * 1024 + h * 64 + n * 16 + lr] = f2bf(o[n][q] * inv);
    }
  }
}

// ---------------- launcher ----------------
extern "C" void kernel_launch(void* const* d_in, const int* in_sizes, int n_in,
                              void* d_out, int out_size, void* d_ws, size_t ws_size,
                              hipStream_t stream) {
  const float* x     = (const float*)d_in[0];
  const float* Wqkv  = (const float*)d_in[1];
  const float* bqkv  = (const float*)d_in[2];
  const float* Wproj = (const float*)d_in[3];
  const float* bproj = (const float*)d_in[4];
  float* out = (float*)d_out;

  char* ws = (char*)d_ws;
  const size_t MB = 1024 * 1024;
  short* x16    = (short*)(ws);             // 8 MB (reused as Y16 after qkv GEMM)
  short* WqkvT  = (short*)(ws + 8 * MB);    // 6 MB
  short* WprojT = (short*)(ws + 14 * MB);   // 2 MB
  short* Q16    = (short*)(ws + 16 * MB);   // 8 MB  [bh][t][64]  (pre-scaled)
  short* K16    = (short*)(ws + 24 * MB);   // 8 MB  [bh][t][64]  (pre-scaled)
  short* VT16   = (short*)(ws + 32 * MB);   // 8 MB  [bh][64][t]
  short* Y16    = x16;                      // 8 MB  [b*t][1024]

  cvt_bf16<<<4096, 256, 0, stream>>>(x, x16, 1048576);
  transpose_cvt<<<dim3(96, 32), dim3(32, 8), 0, stream>>>(Wqkv, WqkvT, 1024, 3072);
  transpose_cvt<<<dim3(32, 32), dim3(32, 8), 0, stream>>>(Wproj, WprojT, 1024, 1024);

  gemm_bf16<0><<<dim3(24, 32), 256, 0, stream>>>(x16, WqkvT, bqkv, nullptr,
                                                 Q16, K16, VT16, 4096, 3072, 1024);
  attn_fwd<<<dim3(32, 32), 256, 0, stream>>>(Q16, K16, VT16, Y16);
  gemm_bf16<1><<<dim3(8, 32), 256, 0, stream>>>(Y16, WprojT, bproj, out,
                                                nullptr, nullptr, nullptr, 4096, 1024, 1024);
}

// Round 2
// 155.667 us; speedup vs baseline: 1.3136x; 1.3136x over previous
//
#include <hip/hip_runtime.h>

typedef __attribute__((ext_vector_type(4))) float fx4;
typedef __attribute__((ext_vector_type(16))) float f32x16;
typedef __attribute__((ext_vector_type(8))) short s16x8;

#define QK_SCALE 0.35355339059327373f  // 1/sqrt(sqrt(64))

__device__ __forceinline__ short f2bf(float f) {
  union { float f; unsigned int u; } v; v.f = f;
  unsigned int r = v.u + 0x7fffu + ((v.u >> 16) & 1u);  // RNE
  return (short)(r >> 16);
}

// XOR swizzle for [rows][64 bf16] LDS tiles (128 B row stride):
// physical byte = (row*128 + cb) ^ ((row&7)<<4). Involution; keeps 16B chunks intact.
__device__ __forceinline__ int swz(int row, int cb) {
  return (row * 128 + cb) ^ ((row & 7) << 4);
}

#define GLL(g, lds) __builtin_amdgcn_global_load_lds( \
    (__attribute__((address_space(1))) void*)(void*)(g), \
    (__attribute__((address_space(3))) void*)(void*)(lds), 16, 0, 0)

// ---------------- conversion kernels ----------------
__global__ __launch_bounds__(256) void cvt_bf16(const float* __restrict__ in,
                                                short* __restrict__ out, int n4) {
  int i = blockIdx.x * 256 + threadIdx.x;
  if (i < n4) {
    float4 v = reinterpret_cast<const float4*>(in)[i];
    short4 o;
    o.x = f2bf(v.x); o.y = f2bf(v.y); o.z = f2bf(v.z); o.w = f2bf(v.w);
    reinterpret_cast<short4*>(out)[i] = o;
  }
}

// W [K][N] fp32 -> WT [N][K] bf16, LDS-tiled (coalesced both sides)
__global__ __launch_bounds__(256) void transpose_cvt(const float* __restrict__ W,
                                                     short* __restrict__ WT,
                                                     int K, int N) {
  __shared__ float tile[32][33];
  int tx = threadIdx.x, ty = threadIdx.y;
  int n0 = blockIdx.x * 32, k0 = blockIdx.y * 32;
#pragma unroll
  for (int i = 0; i < 32; i += 8)
    tile[ty + i][tx] = W[(size_t)(k0 + ty + i) * N + n0 + tx];
  __syncthreads();
#pragma unroll
  for (int i = 0; i < 32; i += 8)
    WT[(size_t)(n0 + ty + i) * K + k0 + tx] = f2bf(tile[tx][ty + i]);
}

// ---------------- GEMM: C[M][N] = A[M][K] @ Bt[N][K]^T (+bias) ----------------
template <int MODE>
__global__ __launch_bounds__(256) void gemm_bf16(
    const short* __restrict__ A, const short* __restrict__ Bt,
    const float* __restrict__ bias, float* __restrict__ Cout,
    short* __restrict__ Qo, short* __restrict__ Ko, short* __restrict__ Vo,
    int M, int N, int K) {
  __shared__ __align__(16) char sA[128 * 64 * 2];
  __shared__ __align__(16) char sB[128 * 64 * 2];
  const int tid = threadIdx.x;
  const int w = tid >> 6, l = tid & 63;
  const int lr = l & 15, lg = l >> 4;
  const int m0 = blockIdx.y * 128, n0 = blockIdx.x * 128;
  const int wr = (w >> 1) * 64, wc = (w & 1) * 64;

  fx4 acc[4][4] = {};

  for (int kt = 0; kt < K; kt += 64) {
#pragma unroll
    for (int i = 0; i < 4; ++i) {
      int c = i * 256 + tid;
      int r = c >> 3, p = c & 7;
      int lch = p ^ (r & 7);
      GLL(A + (size_t)(m0 + r) * K + kt + lch * 8, sA + c * 16);
      GLL(Bt + (size_t)(n0 + r) * K + kt + lch * 8, sB + c * 16);
    }
    __syncthreads();
#pragma unroll
    for (int kk = 0; kk < 2; ++kk) {
      s16x8 av[4], bv[4];
#pragma unroll
      for (int m = 0; m < 4; ++m)
        av[m] = *reinterpret_cast<const s16x8*>(sA + swz(wr + m * 16 + lr, kk * 64 + lg * 16));
#pragma unroll
      for (int n = 0; n < 4; ++n)
        bv[n] = *reinterpret_cast<const s16x8*>(sB + swz(wc + n * 16 + lr, kk * 64 + lg * 16));
#pragma unroll
      for (int m = 0; m < 4; ++m)
#pragma unroll
        for (int n = 0; n < 4; ++n)
          acc[m][n] = __builtin_amdgcn_mfma_f32_16x16x32_bf16(av[m], bv[n], acc[m][n], 0, 0, 0);
    }
    __syncthreads();
  }

#pragma unroll
  for (int m = 0; m < 4; ++m) {
#pragma unroll
    for (int n = 0; n < 4; ++n) {
#pragma unroll
      for (int q = 0; q < 4; ++q) {
        int row = m0 + wr + m * 16 + lg * 4 + q;
        int col = n0 + wc + n * 16 + lr;
        float v = acc[m][n][q] + bias[col];
        if (MODE == 1) {
          Cout[(size_t)row * N + col] = v;
        } else {
          int h = col / 192;
          int rr = col - h * 192;
          int b = row >> 11, t = row & 2047;
          size_t bh = (size_t)b * 16 + h;
          if (rr < 64)
            Qo[(bh * 2048 + t) * 64 + rr] = f2bf(v * QK_SCALE);
          else if (rr < 128)
            Ko[(bh * 2048 + t) * 64 + (rr - 64)] = f2bf(v * QK_SCALE);
          else
            Vo[(bh * 64 + (rr - 128)) * 2048 + t] = f2bf(v);
        }
      }
    }
  }
}

// ---------------- flash attention, swapped-QK^T 32x32 structure ----------------
// 512 blocks (XCD-grouped), 4 waves/block, 32 q-rows/wave, s-tiles of 64.
// S^T = mfma(K, Q): lane owns ONE q-column (q = l&31), 32 s-values in regs
// (partner lane l^32 holds the other 32). Softmax fully in-register.
// O^T = mfma(V^T, P): same lane->q mapping, so m/l/rescale are lane scalars.
__global__ __launch_bounds__(256) void attn_fwd(
    const short* __restrict__ Q, const short* __restrict__ Kc,
    const short* __restrict__ VT, short* __restrict__ Y) {
  __shared__ __align__(16) char sK[2][8192];
  __shared__ __align__(16) char sV[2][8192];
  const int tid = threadIdx.x;
  const int w = tid >> 6, l = tid & 63;
  const int l31 = l & 31, hi = l >> 5;
  // XCD-grouped decode: blocks sharing bh land on the same XCD (bid%8 const)
  const int bid = blockIdx.x;
  const int bh = (bid & 7) * 4 + ((bid >> 3) & 3);
  const int qt = bid >> 5;
  const int q0 = qt * 128 + w * 32;

  // Q fragments: lane holds Q[q0 + l31][k = ks*16 + hi*8 + j]  (B-operand of QK)
  s16x8 qf[4];
  const short* qp = Q + ((size_t)bh * 2048 + q0 + l31) * 64 + hi * 8;
#pragma unroll
  for (int ks = 0; ks < 4; ++ks)
    qf[ks] = *reinterpret_cast<const s16x8*>(qp + ks * 16);

  float m = -1e30f, lsum = 0.f;
  f32x16 o0 = {}, o1 = {};

  // prologue: stage tile 0
#pragma unroll
  for (int i = 0; i < 2; ++i) {
    int c = i * 256 + tid, r = c >> 3, pch = c & 7, lch = pch ^ (r & 7);
    GLL(Kc + ((size_t)bh * 2048 + r) * 64 + lch * 8, sK[0] + c * 16);
    GLL(VT + ((size_t)bh * 64 + r) * 2048 + lch * 8, sV[0] + c * 16);
  }
  __syncthreads();

  for (int sb = 0; sb < 32; ++sb) {
    if (sb < 31) {  // prefetch next tile into other buffer (drained by syncthreads)
      int s1 = (sb + 1) * 64;
#pragma unroll
      for (int i = 0; i < 2; ++i) {
        int c = i * 256 + tid, r = c >> 3, pch = c & 7, lch = pch ^ (r & 7);
        GLL(Kc + ((size_t)bh * 2048 + s1 + r) * 64 + lch * 8, sK[(sb + 1) & 1] + c * 16);
        GLL(VT + ((size_t)bh * 64 + r) * 2048 + s1 + lch * 8, sV[(sb + 1) & 1] + c * 16);
      }
    }
    const char* kb = sK[sb & 1];
    const char* vb = sV[sb & 1];

    // S^T = mfma(A=K, B=Q): D[s][q], col q = l31, rows s = (r&3)+8*(r>>2)+4*hi
    f32x16 p0 = {}, p1 = {};
    __builtin_amdgcn_s_setprio(1);
#pragma unroll
    for (int ks = 0; ks < 4; ++ks) {
      s16x8 ka = *reinterpret_cast<const s16x8*>(kb + swz(l31, ks * 32 + hi * 16));
      p0 = __builtin_amdgcn_mfma_f32_32x32x16_bf16(ka, qf[ks], p0, 0, 0, 0);
    }
#pragma unroll
    for (int ks = 0; ks < 4; ++ks) {
      s16x8 ka = *reinterpret_cast<const s16x8*>(kb + swz(32 + l31, ks * 32 + hi * 16));
      p1 = __builtin_amdgcn_mfma_f32_32x32x16_bf16(ka, qf[ks], p1, 0, 0, 0);
    }
    __builtin_amdgcn_s_setprio(0);

    // --- in-register online softmax (lane's column q = l31) ---
    float a8[8];
#pragma unroll
    for (int i = 0; i < 8; ++i)
      a8[i] = fmaxf(fmaxf(p0[2 * i], p0[2 * i + 1]), fmaxf(p1[2 * i], p1[2 * i + 1]));
    float pm = fmaxf(fmaxf(fmaxf(a8[0], a8[1]), fmaxf(a8[2], a8[3])),
                     fmaxf(fmaxf(a8[4], a8[5]), fmaxf(a8[6], a8[7])));
    pm = fmaxf(pm, __shfl_xor(pm, 32));

    if (!__all(pm <= m + 8.f)) {  // defer-max: skip rescale when max growth small
      float mn = fmaxf(m, pm);
      float al = __expf(m - mn);
      m = mn;
      lsum *= al;
#pragma unroll
      for (int i = 0; i < 16; ++i) { o0[i] *= al; o1[i] *= al; }
    }
#pragma unroll
    for (int i = 0; i < 16; ++i) {
      p0[i] = __expf(p0[i] - m);
      p1[i] = __expf(p1[i] - m);
    }
    float s8[8];
#pragma unroll
    for (int i = 0; i < 8; ++i)
      s8[i] = (p0[2 * i] + p0[2 * i + 1]) + (p1[2 * i] + p1[2 * i + 1]);
    float rs = ((s8[0] + s8[1]) + (s8[2] + s8[3])) + ((s8[4] + s8[5]) + (s8[6] + s8[7]));
    rs += __shfl_xor(rs, 32);
    lsum += rs;

    // P -> packed bf16 words: wd[i] = (p[2i], p[2i+1])
    int wd[16];
#pragma unroll
    for (int i = 0; i < 8; ++i) {
      asm("v_cvt_pk_bf16_f32 %0, %1, %2" : "=v"(wd[i]) : "v"(p0[2 * i]), "v"(p0[2 * i + 1]));
      asm("v_cvt_pk_bf16_f32 %0, %1, %2" : "=v"(wd[8 + i]) : "v"(p1[2 * i]), "v"(p1[2 * i + 1]));
    }

    // O^T += mfma(A=V^T, B=P): per s-step t, B-frag needs P[q][16t + hi*8 + j].
    __builtin_amdgcn_s_setprio(1);
#pragma unroll
    for (int t = 0; t < 4; ++t) {
      int w0 = wd[4 * t], w1 = wd[4 * t + 1], w2 = wd[4 * t + 2], w3 = wd[4 * t + 3];
      int w0x = __shfl_xor(w0, 32), w1x = __shfl_xor(w1, 32);
      int w2x = __shfl_xor(w2, 32), w3x = __shfl_xor(w3, 32);
      union { int i4[4]; s16x8 v; } fr;
      fr.i4[0] = hi ? w2x : w0;
      fr.i4[1] = hi ? w3x : w1;
      fr.i4[2] = hi ? w2 : w0x;
      fr.i4[3] = hi ? w3 : w1x;
      s16x8 v0 = *reinterpret_cast<const s16x8*>(vb + swz(l31, t * 32 + hi * 16));
      o0 = __builtin_amdgcn_mfma_f32_32x32x16_bf16(v0, fr.v, o0, 0, 0, 0);
      s16x8 v1 = *reinterpret_cast<const s16x8*>(vb + swz(32 + l31, t * 32 + hi * 16));
      o1 = __builtin_amdgcn_mfma_f32_32x32x16_bf16(v1, fr.v, o1, 0, 0, 0);
    }
    __builtin_amdgcn_s_setprio(0);
    __syncthreads();
  }

  // epilogue: O^T[d][q]: q = l31, d = (r&3) + 8*(r>>2) + 4*hi (+32 for o1)
  const int b = bh >> 4, h = bh & 15;
  float inv = 1.f / lsum;
  short* yp = Y + ((size_t)b * 2048 + q0 + l31) * 1024 + h * 64 + hi * 4;
#pragma unroll
  for (int gq = 0; gq < 4; ++gq) {
    short4 s4;
    s4.x = f2bf(o0[4 * gq] * inv);     s4.y = f2bf(o0[4 * gq + 1] * inv);
    s4.z = f2bf(o0[4 * gq + 2] * inv); s4.w = f2bf(o0[4 * gq + 3] * inv);
    *reinterpret_cast<short4*>(yp + 8 * gq) = s4;
    s4.x = f2bf(o1[4 * gq] * inv);     s4.y = f2bf(o1[4 * gq + 1] * inv);
    s4.z = f2bf(o1[4 * gq + 2] * inv); s4.w = f2bf(o1[4 * gq + 3] * inv);
    *reinterpret_cast<short4*>(yp + 32 + 8 * gq) = s4;
  }
}

// ---------------- launcher ----------------
extern "C" void kernel_launch(void* const* d_in, const int* in_sizes, int n_in,
                              void* d_out, int out_size, void* d_ws, size_t ws_size,
                              hipStream_t stream) {
  const float* x     = (const float*)d_in[0];
  const float* Wqkv  = (const float*)d_in[1];
  const float* bqkv  = (const float*)d_in[2];
  const float* Wproj = (const float*)d_in[3];
  const float* bproj = (const float*)d_in[4];
  float* out = (float*)d_out;

  char* ws = (char*)d_ws;
  const size_t MB = 1024 * 1024;
  short* x16    = (short*)(ws);             // 8 MB (reused as Y16 after qkv GEMM)
  short* WqkvT  = (short*)(ws + 8 * MB);    // 6 MB
  short* WprojT = (short*)(ws + 14 * MB);   // 2 MB
  short* Q16    = (short*)(ws + 16 * MB);   // 8 MB  [bh][t][64]  (pre-scaled)
  short* K16    = (short*)(ws + 24 * MB);   // 8 MB  [bh][t][64]  (pre-scaled)
  short* VT16   = (short*)(ws + 32 * MB);   // 8 MB  [bh][64][t]
  short* Y16    = x16;                      // 8 MB  [b*t][1024]

  cvt_bf16<<<4096, 256, 0, stream>>>(x, x16, 1048576);
  transpose_cvt<<<dim3(96, 32), dim3(32, 8), 0, stream>>>(Wqkv, WqkvT, 1024, 3072);
  transpose_cvt<<<dim3(32, 32), dim3(32, 8), 0, stream>>>(Wproj, WprojT, 1024, 1024);

  gemm_bf16<0><<<dim3(24, 32), 256, 0, stream>>>(x16, WqkvT, bqkv, nullptr,
                                                 Q16, K16, VT16, 4096, 3072, 1024);
  attn_fwd<<<512, 256, 0, stream>>>(Q16, K16, VT16, Y16);
  gemm_bf16<1><<<dim3(8, 32), 256, 0, stream>>>(Y16, WprojT, bproj, out,
                                                nullptr, nullptr, nullptr, 4096, 1024, 1024);
}

// Round 5
// 146.380 us; speedup vs baseline: 1.3969x; 1.0634x over previous
//
#include <hip/hip_runtime.h>

typedef __attribute__((ext_vector_type(4))) float fx4;
typedef __attribute__((ext_vector_type(16))) float f32x16;
typedef __attribute__((ext_vector_type(8))) short s16x8;
typedef __attribute__((ext_vector_type(2))) unsigned int u32x2;

#define QK_SCALE 0.35355339059327373f   // 1/sqrt(sqrt(64))
#define LOG2E    1.4426950408889634f

__device__ __forceinline__ short f2bf(float f) {
  union { float f; unsigned int u; } v; v.f = f;
  unsigned int r = v.u + 0x7fffu + ((v.u >> 16) & 1u);  // RNE
  return (short)(r >> 16);
}

__device__ __forceinline__ unsigned f2u(float f) {
  union { float f; unsigned u; } v; v.f = f; return v.u;
}
__device__ __forceinline__ float u2f(unsigned u) {
  union { unsigned u; float f; } v; v.u = u; return v.f;
}

// cross-half (lane ^ 32) reduce via permlane32_swap builtin (VALU, no LDS).
__device__ __forceinline__ float xhalf_max(float x) {
  u32x2 r = __builtin_amdgcn_permlane32_swap(f2u(x), f2u(x), false, false);
  return fmaxf(u2f(r[0]), u2f(r[1]));
}
__device__ __forceinline__ float xhalf_sum(float x) {
  u32x2 r = __builtin_amdgcn_permlane32_swap(f2u(x), f2u(x), false, false);
  return u2f(r[0]) + u2f(r[1]);
}

// XOR swizzle for [rows][64 bf16] LDS tiles (128 B row stride).
__device__ __forceinline__ int swz(int row, int cb) {
  return (row * 128 + cb) ^ ((row & 7) << 4);
}

#define GLL(g, lds) __builtin_amdgcn_global_load_lds( \
    (__attribute__((address_space(1))) void*)(void*)(g), \
    (__attribute__((address_space(3))) void*)(void*)(lds), 16, 0, 0)

// ---------------- fused prep: x->bf16, W transposes ----------------
// blocks [0,4096): cvt x; [4096,7168): Wqkv 96x32 tiles; [7168,8192): Wproj 32x32
__global__ __launch_bounds__(256) void prep(
    const float* __restrict__ x, short* __restrict__ x16,
    const float* __restrict__ Wqkv, short* __restrict__ WqkvT,
    const float* __restrict__ Wproj, short* __restrict__ WprojT) {
  const int b = blockIdx.x;
  if (b < 4096) {
    int i = b * 256 + threadIdx.x;
    float4 v = reinterpret_cast<const float4*>(x)[i];
    short4 o;
    o.x = f2bf(v.x); o.y = f2bf(v.y); o.z = f2bf(v.z); o.w = f2bf(v.w);
    reinterpret_cast<short4*>(x16)[i] = o;
    return;
  }
  __shared__ float tile[32][33];
  const float* W; short* WT; int N, bx, by;
  if (b < 7168) { W = Wqkv; WT = WqkvT; N = 3072; int r = b - 4096; bx = r % 96; by = r / 96; }
  else          { W = Wproj; WT = WprojT; N = 1024; int r = b - 7168; bx = r % 32; by = r / 32; }
  const int K = 1024;
  int tx = threadIdx.x & 31, ty = threadIdx.x >> 5;
  int n0 = bx * 32, k0 = by * 32;
#pragma unroll
  for (int i = 0; i < 32; i += 8)
    tile[ty + i][tx] = W[(size_t)(k0 + ty + i) * N + n0 + tx];
  __syncthreads();
#pragma unroll
  for (int i = 0; i < 32; i += 8)
    WT[(size_t)(n0 + ty + i) * K + k0 + tx] = f2bf(tile[tx][ty + i]);
}

// ---------------- GEMM: C[M][N] = A[M][K] @ Bt[N][K]^T (+bias) ----------------
template <int MODE>
__global__ __launch_bounds__(256) void gemm_bf16(
    const short* __restrict__ A, const short* __restrict__ Bt,
    const float* __restrict__ bias, float* __restrict__ Cout,
    short* __restrict__ Qo, short* __restrict__ Ko, short* __restrict__ Vo,
    int M, int N, int K) {
  __shared__ __align__(16) char sA[128 * 64 * 2];
  __shared__ __align__(16) char sB[128 * 64 * 2];
  const int tid = threadIdx.x;
  const int w = tid >> 6, l = tid & 63;
  const int lr = l & 15, lg = l >> 4;
  const int m0 = blockIdx.y * 128, n0 = blockIdx.x * 128;
  const int wr = (w >> 1) * 64, wc = (w & 1) * 64;

  fx4 acc[4][4] = {};

  for (int kt = 0; kt < K; kt += 64) {
#pragma unroll
    for (int i = 0; i < 4; ++i) {
      int c = i * 256 + tid;
      int r = c >> 3, p = c & 7;
      int lch = p ^ (r & 7);
      GLL(A + (size_t)(m0 + r) * K + kt + lch * 8, sA + c * 16);
      GLL(Bt + (size_t)(n0 + r) * K + kt + lch * 8, sB + c * 16);
    }
    __syncthreads();
#pragma unroll
    for (int kk = 0; kk < 2; ++kk) {
      s16x8 av[4], bv[4];
#pragma unroll
      for (int m = 0; m < 4; ++m)
        av[m] = *reinterpret_cast<const s16x8*>(sA + swz(wr + m * 16 + lr, kk * 64 + lg * 16));
#pragma unroll
      for (int n = 0; n < 4; ++n)
        bv[n] = *reinterpret_cast<const s16x8*>(sB + swz(wc + n * 16 + lr, kk * 64 + lg * 16));
#pragma unroll
      for (int m = 0; m < 4; ++m)
#pragma unroll
        for (int n = 0; n < 4; ++n)
          acc[m][n] = __builtin_amdgcn_mfma_f32_16x16x32_bf16(av[m], bv[n], acc[m][n], 0, 0, 0);
    }
    __syncthreads();
  }

#pragma unroll
  for (int m = 0; m < 4; ++m) {
#pragma unroll
    for (int n = 0; n < 4; ++n) {
#pragma unroll
      for (int q = 0; q < 4; ++q) {
        int row = m0 + wr + m * 16 + lg * 4 + q;
        int col = n0 + wc + n * 16 + lr;
        float v = acc[m][n][q] + bias[col];
        if (MODE == 1) {
          Cout[(size_t)row * N + col] = v;
        } else {
          int h = col / 192;
          int rr = col - h * 192;
          int b = row >> 11, t = row & 2047;
          size_t bh = (size_t)b * 16 + h;
          if (rr < 64)
            Qo[(bh * 2048 + t) * 64 + rr] = f2bf(v * (QK_SCALE * LOG2E));  // exp2-domain
          else if (rr < 128)
            Ko[(bh * 2048 + t) * 64 + (rr - 64)] = f2bf(v * QK_SCALE);
          else
            Vo[(bh * 64 + (rr - 128)) * 2048 + t] = f2bf(v);
        }
      }
    }
  }
}

// ---------------- flash attention, swapped-QK^T 32x32, exp2-domain ----------------
// 1024 blocks (XCD-grouped, 4 bh/XCD), 2 waves/block, 32 q-rows/wave, s-tiles of 64.
__global__ __launch_bounds__(128) void attn_fwd(
    const short* __restrict__ Q, const short* __restrict__ Kc,
    const short* __restrict__ VT, short* __restrict__ Y) {
  __shared__ __align__(16) char sK[2][8192];
  __shared__ __align__(16) char sV[2][8192];
  const int tid = threadIdx.x;
  const int w = tid >> 6, l = tid & 63;
  const int l31 = l & 31, hi = l >> 5;
  const int bid = blockIdx.x;
  const int bh = (bid & 7) * 4 + ((bid >> 3) & 3);  // XCD bid&7 owns bh/4 == bid&7
  const int qt = bid >> 5;                          // 0..31
  const int q0 = qt * 64 + w * 32;

  // Q fragments (B-operand of QK): lane holds Q[q0+l31][ks*16 + hi*8 + j]
  s16x8 qf[4];
  const short* qp = Q + ((size_t)bh * 2048 + q0 + l31) * 64 + hi * 8;
#pragma unroll
  for (int ks = 0; ks < 4; ++ks)
    qf[ks] = *reinterpret_cast<const s16x8*>(qp + ks * 16);

  float m = -1e30f, lsum = 0.f;
  f32x16 o0 = {}, o1 = {};

  // prologue: stage tile 0 (512 chunks of 16B per matrix; 128 threads -> 4 iters)
#pragma unroll
  for (int i = 0; i < 4; ++i) {
    int c = i * 128 + tid, r = c >> 3, pch = c & 7, lch = pch ^ (r & 7);
    GLL(Kc + ((size_t)bh * 2048 + r) * 64 + lch * 8, sK[0] + c * 16);
    GLL(VT + ((size_t)bh * 64 + r) * 2048 + lch * 8, sV[0] + c * 16);
  }
  __syncthreads();

  for (int sb = 0; sb < 32; ++sb) {
    if (sb < 31) {  // prefetch next tile (drained by the loop-end syncthreads)
      int s1 = (sb + 1) * 64;
#pragma unroll
      for (int i = 0; i < 4; ++i) {
        int c = i * 128 + tid, r = c >> 3, pch = c & 7, lch = pch ^ (r & 7);
        GLL(Kc + ((size_t)bh * 2048 + s1 + r) * 64 + lch * 8, sK[(sb + 1) & 1] + c * 16);
        GLL(VT + ((size_t)bh * 64 + r) * 2048 + s1 + lch * 8, sV[(sb + 1) & 1] + c * 16);
      }
    }
    const char* kb = sK[sb & 1];
    const char* vb = sV[sb & 1];

    // S^T = mfma(A=K, B=Q): D[s][q], q = l31, s = (r&3)+8*(r>>2)+4*hi (+32 for p1)
    f32x16 p0 = {}, p1 = {};
    __builtin_amdgcn_s_setprio(1);
#pragma unroll
    for (int ks = 0; ks < 4; ++ks) {
      int off = swz(l31, ks * 32 + hi * 16);
      s16x8 ka0 = *reinterpret_cast<const s16x8*>(kb + off);
      s16x8 ka1 = *reinterpret_cast<const s16x8*>(kb + off + 4096);  // rows +32
      p0 = __builtin_amdgcn_mfma_f32_32x32x16_bf16(ka0, qf[ks], p0, 0, 0, 0);
      p1 = __builtin_amdgcn_mfma_f32_32x32x16_bf16(ka1, qf[ks], p1, 0, 0, 0);
    }
    __builtin_amdgcn_s_setprio(0);

    // --- in-register online softmax, base-2 domain ---
    float a8[8];
#pragma unroll
    for (int i = 0; i < 8; ++i)
      a8[i] = fmaxf(fmaxf(p0[2 * i], p0[2 * i + 1]), fmaxf(p1[2 * i], p1[2 * i + 1]));
    float pm = fmaxf(fmaxf(fmaxf(a8[0], a8[1]), fmaxf(a8[2], a8[3])),
                     fmaxf(fmaxf(a8[4], a8[5]), fmaxf(a8[6], a8[7])));
    pm = xhalf_max(pm);  // combine with partner half (lane ^ 32)

    if (!__all(pm <= m + 11.5f)) {  // defer-max (2^11.5 ~= e^8 headroom)
      float mn = fmaxf(m, pm);
      float al = __builtin_amdgcn_exp2f(m - mn);
      m = mn;
      lsum *= al;
#pragma unroll
      for (int i = 0; i < 16; ++i) { o0[i] *= al; o1[i] *= al; }
    }
#pragma unroll
    for (int i = 0; i < 16; ++i) {
      p0[i] = __builtin_amdgcn_exp2f(p0[i] - m);
      p1[i] = __builtin_amdgcn_exp2f(p1[i] - m);
    }
    float s8[8];
#pragma unroll
    for (int i = 0; i < 8; ++i)
      s8[i] = (p0[2 * i] + p0[2 * i + 1]) + (p1[2 * i] + p1[2 * i + 1]);
    float rs = ((s8[0] + s8[1]) + (s8[2] + s8[3])) + ((s8[4] + s8[5]) + (s8[6] + s8[7]));
    lsum += xhalf_sum(rs);

    // P -> packed bf16 words: wd[i] = (p[2i], p[2i+1])
    int wd[16];
#pragma unroll
    for (int i = 0; i < 8; ++i) {
      asm("v_cvt_pk_bf16_f32 %0, %1, %2" : "=v"(wd[i]) : "v"(p0[2 * i]), "v"(p0[2 * i + 1]));
      asm("v_cvt_pk_bf16_f32 %0, %1, %2" : "=v"(wd[8 + i]) : "v"(p1[2 * i]), "v"(p1[2 * i + 1]));
    }

    // O^T += mfma(A=V^T, B=P). permlane32_swap(a,b) -> {a': lo=a.lo, hi=b.lo;
    // b': lo=a.hi, hi=b.hi}. With a=wd[4t], b=wd[4t+2]:
    //   lo lanes: fr = {own wd0, own wd1, partner wd0, partner wd1}
    //   hi lanes: fr = {partner wd2, partner wd3, own wd2, own wd3}
    // which is exactly the B-frag word set for k = 16t + hi*8 + j.
    __builtin_amdgcn_s_setprio(1);
#pragma unroll
    for (int t = 0; t < 4; ++t) {
      u32x2 s02 = __builtin_amdgcn_permlane32_swap(
          (unsigned)wd[4 * t], (unsigned)wd[4 * t + 2], false, false);
      u32x2 s13 = __builtin_amdgcn_permlane32_swap(
          (unsigned)wd[4 * t + 1], (unsigned)wd[4 * t + 3], false, false);
      union { unsigned i4[4]; s16x8 v; } fr;
      fr.i4[0] = s02[0]; fr.i4[1] = s13[0]; fr.i4[2] = s02[1]; fr.i4[3] = s13[1];
      int off = swz(l31, t * 32 + hi * 16);
      s16x8 v0 = *reinterpret_cast<const s16x8*>(vb + off);
      s16x8 v1 = *reinterpret_cast<const s16x8*>(vb + off + 4096);
      o0 = __builtin_amdgcn_mfma_f32_32x32x16_bf16(v0, fr.v, o0, 0, 0, 0);
      o1 = __builtin_amdgcn_mfma_f32_32x32x16_bf16(v1, fr.v, o1, 0, 0, 0);
    }
    __builtin_amdgcn_s_setprio(0);
    __syncthreads();
  }

  // epilogue: O^T[d][q]: q = l31, d = (r&3)+8*(r>>2)+4*hi (+32 for o1)
  const int b = bh >> 4, h = bh & 15;
  float inv = 1.f / lsum;
  short* yp = Y + ((size_t)b * 2048 + q0 + l31) * 1024 + h * 64 + hi * 4;
#pragma unroll
  for (int gq = 0; gq < 4; ++gq) {
    short4 s4;
    s4.x = f2bf(o0[4 * gq] * inv);     s4.y = f2bf(o0[4 * gq + 1] * inv);
    s4.z = f2bf(o0[4 * gq + 2] * inv); s4.w = f2bf(o0[4 * gq + 3] * inv);
    *reinterpret_cast<short4*>(yp + 8 * gq) = s4;
    s4.x = f2bf(o1[4 * gq] * inv);     s4.y = f2bf(o1[4 * gq + 1] * inv);
    s4.z = f2bf(o1[4 * gq + 2] * inv); s4.w = f2bf(o1[4 * gq + 3] * inv);
    *reinterpret_cast<short4*>(yp + 32 + 8 * gq) = s4;
  }
}

// ---------------- launcher ----------------
extern "C" void kernel_launch(void* const* d_in, const int* in_sizes, int n_in,
                              void* d_out, int out_size, void* d_ws, size_t ws_size,
                              hipStream_t stream) {
  const float* x     = (const float*)d_in[0];
  const float* Wqkv  = (const float*)d_in[1];
  const float* bqkv  = (const float*)d_in[2];
  const float* Wproj = (const float*)d_in[3];
  const float* bproj = (const float*)d_in[4];
  float* out = (float*)d_out;

  char* ws = (char*)d_ws;
  const size_t MB = 1024 * 1024;
  short* x16    = (short*)(ws);             // 8 MB (reused as Y16 after qkv GEMM)
  short* WqkvT  = (short*)(ws + 8 * MB);    // 6 MB
  short* WprojT = (short*)(ws + 14 * MB);   // 2 MB
  short* Q16    = (short*)(ws + 16 * MB);   // 8 MB  [bh][t][64]  (scaled by s*log2e)
  short* K16    = (short*)(ws + 24 * MB);   // 8 MB  [bh][t][64]  (scaled by s)
  short* VT16   = (short*)(ws + 32 * MB);   // 8 MB  [bh][64][t]
  short* Y16    = x16;                      // 8 MB  [b*t][1024]

  prep<<<8192, 256, 0, stream>>>(x, x16, Wqkv, WqkvT, Wproj, WprojT);
  gemm_bf16<0><<<dim3(24, 32), 256, 0, stream>>>(x16, WqkvT, bqkv, nullptr,
                                                 Q16, K16, VT16, 4096, 3072, 1024);
  attn_fwd<<<1024, 128, 0, stream>>>(Q16, K16, VT16, Y16);
  gemm_bf16<1><<<dim3(8, 32), 256, 0, stream>>>(Y16, WprojT, bproj, out,
                                                nullptr, nullptr, nullptr, 4096, 1024, 1024);
}